// Round 8
// baseline (483.702 us; speedup 1.0000x reference)
//
#include <hip/hip_runtime.h>
#include <hip/hip_bf16.h>
#include <hip/hip_fp16.h>

// Problem constants (fixed by the reference)
#define N_GENES_MAX 5000
#define PARAMS_PER_GENE 445

// Per-bin record: {loc[b], loc[b+1], cdf[b], pack(h[b] f16 | h[b+1] f16 << 16)}
// One 16B gather fully determines a stage evaluation.
__device__ float4 g_rec0[(size_t)N_GENES_MAX * 127];
__device__ float4 g_rec1[(size_t)N_GENES_MAX * 63];
__device__ float4 g_rec2[(size_t)N_GENES_MAX * 31];

static __device__ __forceinline__ unsigned f2h(float f) {
    union { __half h; unsigned short u; } c;
    c.h = __float2half_rn(f);
    return (unsigned)c.u;
}
static __device__ __forceinline__ float h2f(unsigned u) {
    union { unsigned short u; __half h; } c;
    c.u = (unsigned short)u;
    return __half2float(c.h);
}

// ---------------------------------------------------------------------------
// Kernel 1: build per-(gene,stage) bin records. grid=(G,3), block=128.
// LDS/barrier implementation — numerics identical to the R3-R5 verified
// builder; only the final store format changed (float4 record + s_hgt pass).
// ---------------------------------------------------------------------------
__global__ void build_knots(const float* __restrict__ params) {
    const int g = blockIdx.x;
    const int t = blockIdx.y;
    const int ns[3]   = {128, 64, 32};
    const int poff[3] = {0, 255, 382};   // heights start within gene's 445 params

    const int n = ns[t];
    const int m = n - 1;
    const float* ph = params + (size_t)g * PARAMS_PER_GENE + poff[t];
    const float* pw = ph + n;

    __shared__ float s_scan[128];
    __shared__ float s_h[129];
    __shared__ float s_red[128];
    __shared__ float s_loc[128];
    __shared__ float s_cdf[128];
    __shared__ float s_hgt[128];

    const int tid = threadIdx.x;

    // ---- softmax over widths ----
    float uw = (tid < m) ? pw[tid] : -1e30f;
    s_red[tid] = uw;
    __syncthreads();
    for (int s = 64; s > 0; s >>= 1) {
        if (tid < s) s_red[tid] = fmaxf(s_red[tid], s_red[tid + s]);
        __syncthreads();
    }
    const float mx = s_red[0];
    __syncthreads();
    float e = (tid < m) ? expf(uw - mx) : 0.0f;

    // inclusive scan of e (Hillis-Steele; tails zero)
    s_scan[tid] = e;
    __syncthreads();
    #pragma unroll
    for (int off = 1; off < 128; off <<= 1) {
        float v = (tid >= off) ? s_scan[tid - off] : 0.0f;
        __syncthreads();
        s_scan[tid] += v;
        __syncthreads();
    }
    const float S = s_scan[m - 1];
    const float invS = 1.0f / S;
    if (tid == 0) s_loc[0] = 0.0f;
    if (tid < m) s_loc[tid + 1] = (tid == m - 1) ? 1.0f : s_scan[tid] * invS;
    const float w_i = e * invS;          // widths[tid], valid tid < m
    __syncthreads();

    // ---- heights ----
    float uh = (tid < n) ? ph[tid] : 0.0f;
    float eh = (tid < n) ? expf(uh) : 0.0f;
    s_h[tid] = eh;
    if (tid == 0) s_h[128] = 0.0f;
    __syncthreads();
    float term = (tid < m) ? 0.5f * (s_h[tid] + s_h[tid + 1]) * w_i : 0.0f;
    s_red[tid] = term;
    __syncthreads();
    for (int s = 64; s > 0; s >>= 1) {
        if (tid < s) s_red[tid] += s_red[tid + s];
        __syncthreads();
    }
    const float area = s_red[0];
    __syncthreads();
    const float inv_area = 1.0f / area;
    if (tid < n) s_hgt[tid] = eh * inv_area;

    // ---- left CDF: inclusive scan of 0.5*(h[i]+h[i+1])*w[i] ----
    float d = term * inv_area;
    s_scan[tid] = d;
    __syncthreads();
    #pragma unroll
    for (int off = 1; off < 128; off <<= 1) {
        float v = (tid >= off) ? s_scan[tid - off] : 0.0f;
        __syncthreads();
        s_scan[tid] += v;
        __syncthreads();
    }
    if (tid == 0) s_cdf[0] = 0.0f;
    if (tid < m) s_cdf[tid + 1] = (tid == m - 1) ? 1.0f : s_scan[tid];
    __syncthreads();

    // ---- emit per-bin records ----
    if (tid < m) {
        float4 r;
        r.x = s_loc[tid];
        r.y = s_loc[tid + 1];
        r.z = s_cdf[tid];
        r.w = __uint_as_float((f2h(s_hgt[tid + 1]) << 16) | f2h(s_hgt[tid]));
        if (t == 0)      g_rec0[(size_t)g * 127 + tid] = r;
        else if (t == 1) g_rec1[(size_t)g * 63 + tid] = r;
        else             g_rec2[(size_t)g * 31 + tid] = r;
    }
}

// ---------------------------------------------------------------------------
// Kernel 2: per-element evaluation — ONE 16B gather per stage (+ rare walk).
// ---------------------------------------------------------------------------
template <int K>
static __device__ __forceinline__ void stage(const float4* __restrict__ rec,
                                             float& x, float& lad) {
    // b converges to clip(searchsorted(locs, x, 'right') - 1, 0, K-2).
    int b = (int)(x * (float)(K - 1));
    b = (b < 0) ? 0 : ((b > K - 2) ? K - 2 : b);
    float4 r = rec[b];
    while (b > 0 && r.x > x) { --b; r = rec[b]; }
    while (b < K - 2 && r.y <= x) { ++b; r = rec[b]; }
    const float w = r.y - r.x;
    const float alpha = (x - r.x) / w;
    const unsigned hp = __float_as_uint(r.w);
    const float lh = h2f(hp & 0xffffu);
    const float rh = h2f(hp >> 16);
    float o = (0.5f * (rh - lh) * w) * alpha * alpha + (lh * w) * alpha + r.z;
    o = fminf(fmaxf(o, 0.0f), 1.0f);
    lad += __logf(alpha * (rh - lh) + lh);
    x = o;
}

static __device__ __forceinline__ void eval_one(float& x, int g, float& lad) {
    stage<128>(g_rec0 + (size_t)g * 127, x, lad);
    stage<64> (g_rec1 + (size_t)g * 63,  x, lad);
    stage<32> (g_rec2 + (size_t)g * 31,  x, lad);
}

__global__ void spline_eval(const float* __restrict__ x_in,
                            const int* __restrict__ gix,
                            float* __restrict__ out, int N) {
    const int i = blockIdx.x * blockDim.x + threadIdx.x;
    const int i2 = i * 2;
    if (i2 + 1 < N) {
        const float2 xv = *(const float2*)(x_in + i2);
        const int2   gv = *(const int2*)(gix + i2);
        float x0 = xv.x, x1 = xv.y;
        float l0 = 0.0f, l1 = 0.0f;
        eval_one(x0, gv.x, l0);
        eval_one(x1, gv.y, l1);
        *(float2*)(out + i2)     = make_float2(x0, x1);
        *(float2*)(out + N + i2) = make_float2(l0, l1);
    } else if (i2 < N) {
        float x0 = x_in[i2];
        float l0 = 0.0f;
        eval_one(x0, gix[i2], l0);
        out[i2] = x0;
        out[N + i2] = l0;
    }
}

// ---------------------------------------------------------------------------
extern "C" void kernel_launch(void* const* d_in, const int* in_sizes, int n_in,
                              void* d_out, int out_size, void* d_ws, size_t ws_size,
                              hipStream_t stream) {
    const float* x      = (const float*)d_in[0];
    const int*   gix    = (const int*)d_in[1];
    const float* params = (const float*)d_in[2];
    float* out = (float*)d_out;

    const int N = in_sizes[0];
    const int G = in_sizes[2] / PARAMS_PER_GENE;

    build_knots<<<dim3(G, 3), 128, 0, stream>>>(params);

    const int block = 256;
    const int nh = (N + 1) / 2;
    spline_eval<<<(nh + block - 1) / block, block, 0, stream>>>(x, gix, out, N);
}

// Round 9
// 206.564 us; speedup vs baseline: 2.3417x; 2.3417x over previous
//
#include <hip/hip_runtime.h>
#include <hip/hip_bf16.h>
#include <hip/hip_fp16.h>

// Problem constants (fixed by the reference)
#define N_GENES_MAX 5000
#define PARAMS_PER_GENE 445

// Packed knot (8B): {loc f32; y = (h f16 << 16) | (cdf-loc) f16}.
// delta-encoding keeps cdf at ~f32 absolute accuracy (|cdf-loc| ~ 1e-2,
// f16 abs err ~1.5e-5) while halving the table vs 16B records: 8.96 MB
// total -> much better per-XCD L2 residency (the R7 lesson: eval dur ~=
// L2-fill bytes / 3.5 TB/s).
__device__ uint2 g_k0[(size_t)N_GENES_MAX * 128];
__device__ uint2 g_k1[(size_t)N_GENES_MAX * 64];
__device__ uint2 g_k2[(size_t)N_GENES_MAX * 32];

static __device__ __forceinline__ unsigned f2h(float f) {
    union { __half h; unsigned short u; } c;
    c.h = __float2half_rn(f);
    return (unsigned)c.u;
}
static __device__ __forceinline__ float h2f(unsigned u) {
    union { unsigned short u; __half h; } c;
    c.u = (unsigned short)u;
    return __half2float(c.h);
}

// ---- wave-level primitives (64 lanes) ----
static __device__ __forceinline__ float wscan_incl(float v) {
    const int lane = threadIdx.x & 63;
    #pragma unroll
    for (int off = 1; off < 64; off <<= 1) {
        float u = __shfl_up(v, off, 64);
        if (lane >= off) v += u;
    }
    return v;
}
static __device__ __forceinline__ float wmax64(float v) {
    #pragma unroll
    for (int off = 32; off > 0; off >>= 1) v = fmaxf(v, __shfl_xor(v, off, 64));
    return v;
}
static __device__ __forceinline__ float wsum64(float v) {
    #pragma unroll
    for (int off = 32; off > 0; off >>= 1) v += __shfl_xor(v, off, 64);
    return v;
}

// ---------------------------------------------------------------------------
// Kernel 1: build per-(gene,stage) knots. grid=(G,3), block=128 (2 waves).
// Math/index structure identical to the R8-verified LDS builder; only the
// scan/reduce internals use wave shuffles (9 barriers instead of ~56).
// ---------------------------------------------------------------------------
__global__ void build_knots(const float* __restrict__ params) {
    const int g = blockIdx.x;
    const int t = blockIdx.y;
    const int ns[3]   = {128, 64, 32};
    const int poff[3] = {0, 255, 382};

    const int n = ns[t];
    const int m = n - 1;
    const float* ph = params + (size_t)g * PARAMS_PER_GENE + poff[t];
    const float* pw = ph + n;

    __shared__ float s2[2];
    __shared__ float s_scan[128];
    __shared__ float s_h[129];
    __shared__ float s_loc[128];
    __shared__ float s_cdf[128];

    const int tid  = threadIdx.x;
    const int lane = tid & 63;
    const int wv   = tid >> 6;

    // ---- softmax max over widths ----
    const float uw = (tid < m) ? pw[tid] : -1e30f;
    float vmax = wmax64(uw);
    if (lane == 0) s2[wv] = vmax;
    __syncthreads();                               // B1
    const float mx = fmaxf(s2[0], s2[1]);
    __syncthreads();                               // B2 (s2 safe for reuse)

    const float e = (tid < m) ? __expf(uw - mx) : 0.0f;

    // ---- block inclusive scan of e ----
    float sc = wscan_incl(e);
    if (lane == 63) s2[wv] = sc;
    __syncthreads();                               // B3
    if (wv == 1) sc += s2[0];
    s_scan[tid] = sc;
    __syncthreads();                               // B4 (s_scan ready; s2 safe)

    const float S = s_scan[m - 1];
    const float invS = 1.0f / S;
    if (tid == 0) s_loc[0] = 0.0f;
    if (tid < m) s_loc[tid + 1] = (tid == m - 1) ? 1.0f : s_scan[tid] * invS;
    const float w_i = e * invS;                    // widths[tid], tid < m

    // ---- heights ----
    const float eh = (tid < n) ? __expf(ph[tid]) : 0.0f;
    s_h[tid] = eh;
    if (tid == 0) s_h[128] = 0.0f;
    __syncthreads();                               // B5 (s_loc, s_h ready)

    const float term = (tid < m) ? 0.5f * (s_h[tid] + s_h[tid + 1]) * w_i : 0.0f;
    float ts = wsum64(term);
    if (lane == 0) s2[wv] = ts;
    __syncthreads();                               // B6
    const float area = s2[0] + s2[1];
    __syncthreads();                               // B7 (s2 safe for reuse)

    const float ia = 1.0f / area;
    const float hgt = eh * ia;                     // heights[tid], tid < n

    // ---- block inclusive scan of d = term*ia ----
    float c = wscan_incl(term * ia);
    if (lane == 63) s2[wv] = c;
    __syncthreads();                               // B8
    if (wv == 1) c += s2[0];
    s_scan[tid] = c;
    __syncthreads();                               // B9 (s_scan ready)

    if (tid == 0) s_cdf[0] = 0.0f;
    if (tid < m) s_cdf[tid + 1] = (tid == m - 1) ? 1.0f : s_scan[tid];
    __syncthreads();                               // B10 (s_cdf ready)

    // ---- emit knots: {loc f32, (h f16 <<16)|(cdf-loc) f16} ----
    if (tid < n) {
        const float loc = s_loc[tid];
        uint2 kt;
        kt.x = __float_as_uint(loc);
        kt.y = (f2h(hgt) << 16) | f2h(s_cdf[tid] - loc);
        if (t == 0)      g_k0[(size_t)g * 128 + tid] = kt;
        else if (t == 1) g_k1[(size_t)g * 64 + tid] = kt;
        else             g_k2[(size_t)g * 32 + tid] = kt;
    }
}

// ---------------------------------------------------------------------------
// Kernel 2: per-element evaluation — 2 adjacent 8B knots per stage.
// ---------------------------------------------------------------------------
template <int K>
static __device__ __forceinline__ void stage(const uint2* __restrict__ kn,
                                             float& x, float& lad) {
    // b converges to clip(searchsorted(locs, x, 'right') - 1, 0, K-2).
    int b = (int)(x * (float)(K - 1));
    b = (b < 0) ? 0 : ((b > K - 2) ? K - 2 : b);
    uint2 k0 = kn[b];
    uint2 k1 = kn[b + 1];
    float l0 = __uint_as_float(k0.x);
    float l1 = __uint_as_float(k1.x);
    while (b > 0 && l0 > x) {
        --b;
        k1 = k0; l1 = l0;
        k0 = kn[b]; l0 = __uint_as_float(k0.x);
    }
    while (b < K - 2 && l1 <= x) {
        ++b;
        k0 = k1; l0 = l1;
        k1 = kn[b + 1]; l1 = __uint_as_float(k1.x);
    }
    const float lh = h2f(k0.y >> 16);
    const float rh = h2f(k1.y >> 16);
    const float lc = l0 + h2f(k0.y & 0xffffu);   // cdf[b] = loc[b] + delta
    const float w  = l1 - l0;
    const float alpha = (x - l0) / w;
    float o = (0.5f * (rh - lh) * w) * alpha * alpha + (lh * w) * alpha + lc;
    o = fminf(fmaxf(o, 0.0f), 1.0f);
    lad += __logf(alpha * (rh - lh) + lh);
    x = o;
}

static __device__ __forceinline__ void eval_one(float& x, int g, float& lad) {
    stage<128>(g_k0 + (size_t)g * 128, x, lad);
    stage<64> (g_k1 + (size_t)g * 64,  x, lad);
    stage<32> (g_k2 + (size_t)g * 32,  x, lad);
}

typedef float fvec2 __attribute__((ext_vector_type(2)));
typedef int   ivec2 __attribute__((ext_vector_type(2)));

__global__ void spline_eval(const float* __restrict__ x_in,
                            const int* __restrict__ gix,
                            float* __restrict__ out, int N) {
    const int i = blockIdx.x * blockDim.x + threadIdx.x;
    const int i2 = i * 2;
    if (i2 + 1 < N) {
        // non-temporal streaming: keep L2 lines for the knot tables
        const fvec2 xv = __builtin_nontemporal_load((const fvec2*)(x_in + i2));
        const ivec2 gv = __builtin_nontemporal_load((const ivec2*)(gix + i2));
        float x0 = xv.x, x1 = xv.y;
        float l0 = 0.0f, l1 = 0.0f;
        eval_one(x0, gv.x, l0);
        eval_one(x1, gv.y, l1);
        fvec2 o0; o0.x = x0; o0.y = x1;
        fvec2 o1; o1.x = l0; o1.y = l1;
        __builtin_nontemporal_store(o0, (fvec2*)(out + i2));
        __builtin_nontemporal_store(o1, (fvec2*)(out + N + i2));
    } else if (i2 < N) {
        float x0 = x_in[i2];
        float l0 = 0.0f;
        eval_one(x0, gix[i2], l0);
        out[i2] = x0;
        out[N + i2] = l0;
    }
}

// ---------------------------------------------------------------------------
extern "C" void kernel_launch(void* const* d_in, const int* in_sizes, int n_in,
                              void* d_out, int out_size, void* d_ws, size_t ws_size,
                              hipStream_t stream) {
    const float* x      = (const float*)d_in[0];
    const int*   gix    = (const int*)d_in[1];
    const float* params = (const float*)d_in[2];
    float* out = (float*)d_out;

    const int N = in_sizes[0];
    const int G = in_sizes[2] / PARAMS_PER_GENE;

    build_knots<<<dim3(G, 3), 128, 0, stream>>>(params);

    const int block = 256;
    const int nh = (N + 1) / 2;
    spline_eval<<<(nh + block - 1) / block, block, 0, stream>>>(x, gix, out, N);
}

// Round 10
// 189.721 us; speedup vs baseline: 2.5495x; 1.0888x over previous
//
#include <hip/hip_runtime.h>
#include <hip/hip_bf16.h>
#include <hip/hip_fp16.h>

// Problem constants (fixed by the reference)
#define N_GENES_MAX 5000
#define N_ELEM_MAX  4000000
#define PARAMS_PER_GENE 445

// Packed knot (8B): {loc f32; y = (h f16 << 16) | (cdf-loc) f16}.
// Two-pass stage split (R9): pass A touches only g_k0 (5.0 MB ~ per-XCD L2),
// pass B touches g_k1+g_k2 (3.75 MB, fully L2-resident). Midstate between
// passes: uint2 {x' f32, (gene << 16) | lad0 f16} — 8B/elem coalesced.
__device__ uint2 g_k0[(size_t)N_GENES_MAX * 128];
__device__ uint2 g_k1[(size_t)N_GENES_MAX * 64];
__device__ uint2 g_k2[(size_t)N_GENES_MAX * 32];
__device__ uint2 g_mid[N_ELEM_MAX];

static __device__ __forceinline__ unsigned f2h(float f) {
    union { __half h; unsigned short u; } c;
    c.h = __float2half_rn(f);
    return (unsigned)c.u;
}
static __device__ __forceinline__ float h2f(unsigned u) {
    union { unsigned short u; __half h; } c;
    c.u = (unsigned short)u;
    return __half2float(c.h);
}

// ---- wave-level primitives (64 lanes) ----
static __device__ __forceinline__ float wscan_incl(float v) {
    const int lane = threadIdx.x & 63;
    #pragma unroll
    for (int off = 1; off < 64; off <<= 1) {
        float u = __shfl_up(v, off, 64);
        if (lane >= off) v += u;
    }
    return v;
}
static __device__ __forceinline__ float wmax64(float v) {
    #pragma unroll
    for (int off = 32; off > 0; off >>= 1) v = fmaxf(v, __shfl_xor(v, off, 64));
    return v;
}
static __device__ __forceinline__ float wsum64(float v) {
    #pragma unroll
    for (int off = 32; off > 0; off >>= 1) v += __shfl_xor(v, off, 64);
    return v;
}

// ---------------------------------------------------------------------------
// Kernel 1: build per-(gene,stage) knots. grid=(G,3), block=128 (2 waves).
// (R8-verified: wave-shuffle scans + 2-element LDS cross-wave combine.)
// ---------------------------------------------------------------------------
__global__ void build_knots(const float* __restrict__ params) {
    const int g = blockIdx.x;
    const int t = blockIdx.y;
    const int ns[3]   = {128, 64, 32};
    const int poff[3] = {0, 255, 382};

    const int n = ns[t];
    const int m = n - 1;
    const float* ph = params + (size_t)g * PARAMS_PER_GENE + poff[t];
    const float* pw = ph + n;

    __shared__ float s2[2];
    __shared__ float s_scan[128];
    __shared__ float s_h[129];
    __shared__ float s_loc[128];
    __shared__ float s_cdf[128];

    const int tid  = threadIdx.x;
    const int lane = tid & 63;
    const int wv   = tid >> 6;

    const float uw = (tid < m) ? pw[tid] : -1e30f;
    float vmax = wmax64(uw);
    if (lane == 0) s2[wv] = vmax;
    __syncthreads();
    const float mx = fmaxf(s2[0], s2[1]);
    __syncthreads();

    const float e = (tid < m) ? __expf(uw - mx) : 0.0f;

    float sc = wscan_incl(e);
    if (lane == 63) s2[wv] = sc;
    __syncthreads();
    if (wv == 1) sc += s2[0];
    s_scan[tid] = sc;
    __syncthreads();

    const float S = s_scan[m - 1];
    const float invS = 1.0f / S;
    if (tid == 0) s_loc[0] = 0.0f;
    if (tid < m) s_loc[tid + 1] = (tid == m - 1) ? 1.0f : s_scan[tid] * invS;
    const float w_i = e * invS;

    const float eh = (tid < n) ? __expf(ph[tid]) : 0.0f;
    s_h[tid] = eh;
    if (tid == 0) s_h[128] = 0.0f;
    __syncthreads();

    const float term = (tid < m) ? 0.5f * (s_h[tid] + s_h[tid + 1]) * w_i : 0.0f;
    float ts = wsum64(term);
    if (lane == 0) s2[wv] = ts;
    __syncthreads();
    const float area = s2[0] + s2[1];
    __syncthreads();

    const float ia = 1.0f / area;
    const float hgt = eh * ia;

    float c = wscan_incl(term * ia);
    if (lane == 63) s2[wv] = c;
    __syncthreads();
    if (wv == 1) c += s2[0];
    s_scan[tid] = c;
    __syncthreads();

    if (tid == 0) s_cdf[0] = 0.0f;
    if (tid < m) s_cdf[tid + 1] = (tid == m - 1) ? 1.0f : s_scan[tid];
    __syncthreads();

    if (tid < n) {
        const float loc = s_loc[tid];
        uint2 kt;
        kt.x = __float_as_uint(loc);
        kt.y = (f2h(hgt) << 16) | f2h(s_cdf[tid] - loc);
        if (t == 0)      g_k0[(size_t)g * 128 + tid] = kt;
        else if (t == 1) g_k1[(size_t)g * 64 + tid] = kt;
        else             g_k2[(size_t)g * 32 + tid] = kt;
    }
}

// ---------------------------------------------------------------------------
// Stage evaluation from packed knots (verified R8 logic).
// ---------------------------------------------------------------------------
template <int K>
static __device__ __forceinline__ void stage(const uint2* __restrict__ kn,
                                             float& x, float& lad) {
    int b = (int)(x * (float)(K - 1));
    b = (b < 0) ? 0 : ((b > K - 2) ? K - 2 : b);
    uint2 k0 = kn[b];
    uint2 k1 = kn[b + 1];
    float l0 = __uint_as_float(k0.x);
    float l1 = __uint_as_float(k1.x);
    while (b > 0 && l0 > x) {
        --b;
        k1 = k0; l1 = l0;
        k0 = kn[b]; l0 = __uint_as_float(k0.x);
    }
    while (b < K - 2 && l1 <= x) {
        ++b;
        k0 = k1; l0 = l1;
        k1 = kn[b + 1]; l1 = __uint_as_float(k1.x);
    }
    const float lh = h2f(k0.y >> 16);
    const float rh = h2f(k1.y >> 16);
    const float lc = l0 + h2f(k0.y & 0xffffu);
    const float w  = l1 - l0;
    const float alpha = (x - l0) / w;
    float o = (0.5f * (rh - lh) * w) * alpha * alpha + (lh * w) * alpha + lc;
    o = fminf(fmaxf(o, 0.0f), 1.0f);
    lad += __logf(alpha * (rh - lh) + lh);
    x = o;
}

typedef float fvec2 __attribute__((ext_vector_type(2)));
typedef int   ivec2 __attribute__((ext_vector_type(2)));
typedef unsigned uvec4 __attribute__((ext_vector_type(4)));

// ---------------------------------------------------------------------------
// Kernel 2a: pass A — stage0 only (table 5.0 MB). Writes midstate.
// ---------------------------------------------------------------------------
__global__ void spline_evalA(const float* __restrict__ x_in,
                             const int* __restrict__ gix, int N) {
    const int i = blockIdx.x * blockDim.x + threadIdx.x;
    const int i2 = i * 2;
    if (i2 + 1 < N) {
        const fvec2 xv = __builtin_nontemporal_load((const fvec2*)(x_in + i2));
        const ivec2 gv = __builtin_nontemporal_load((const ivec2*)(gix + i2));
        float x0 = xv.x, x1 = xv.y;
        float l0 = 0.0f, l1 = 0.0f;
        stage<128>(g_k0 + (size_t)gv.x * 128, x0, l0);
        stage<128>(g_k0 + (size_t)gv.y * 128, x1, l1);
        uvec4 mid;
        mid.x = __float_as_uint(x0);
        mid.y = ((unsigned)gv.x << 16) | f2h(l0);
        mid.z = __float_as_uint(x1);
        mid.w = ((unsigned)gv.y << 16) | f2h(l1);
        __builtin_nontemporal_store(mid, (uvec4*)(g_mid + i2));
    } else if (i2 < N) {
        float x0 = x_in[i2];
        float l0 = 0.0f;
        const int g = gix[i2];
        stage<128>(g_k0 + (size_t)g * 128, x0, l0);
        uint2 m;
        m.x = __float_as_uint(x0);
        m.y = ((unsigned)g << 16) | f2h(l0);
        g_mid[i2] = m;
    }
}

// ---------------------------------------------------------------------------
// Kernel 2b: pass B — stages 1+2 (tables 3.75 MB, L2-resident). Writes out.
// ---------------------------------------------------------------------------
__global__ void spline_evalB(float* __restrict__ out, int N) {
    const int i = blockIdx.x * blockDim.x + threadIdx.x;
    const int i2 = i * 2;
    if (i2 + 1 < N) {
        const uvec4 mid = __builtin_nontemporal_load((const uvec4*)(g_mid + i2));
        float x0 = __uint_as_float(mid.x);
        float x1 = __uint_as_float(mid.z);
        const int g0 = (int)(mid.y >> 16);
        const int g1 = (int)(mid.w >> 16);
        float l0 = h2f(mid.y & 0xffffu);
        float l1 = h2f(mid.w & 0xffffu);
        stage<64>(g_k1 + (size_t)g0 * 64, x0, l0);
        stage<64>(g_k1 + (size_t)g1 * 64, x1, l1);
        stage<32>(g_k2 + (size_t)g0 * 32, x0, l0);
        stage<32>(g_k2 + (size_t)g1 * 32, x1, l1);
        fvec2 o0; o0.x = x0; o0.y = x1;
        fvec2 o1; o1.x = l0; o1.y = l1;
        __builtin_nontemporal_store(o0, (fvec2*)(out + i2));
        __builtin_nontemporal_store(o1, (fvec2*)(out + N + i2));
    } else if (i2 < N) {
        const uint2 mid = g_mid[i2];
        float x0 = __uint_as_float(mid.x);
        const int g0 = (int)(mid.y >> 16);
        float l0 = h2f(mid.y & 0xffffu);
        stage<64>(g_k1 + (size_t)g0 * 64, x0, l0);
        stage<32>(g_k2 + (size_t)g0 * 32, x0, l0);
        out[i2] = x0;
        out[N + i2] = l0;
    }
}

// ---------------------------------------------------------------------------
extern "C" void kernel_launch(void* const* d_in, const int* in_sizes, int n_in,
                              void* d_out, int out_size, void* d_ws, size_t ws_size,
                              hipStream_t stream) {
    const float* x      = (const float*)d_in[0];
    const int*   gix    = (const int*)d_in[1];
    const float* params = (const float*)d_in[2];
    float* out = (float*)d_out;

    const int N = in_sizes[0];
    const int G = in_sizes[2] / PARAMS_PER_GENE;

    build_knots<<<dim3(G, 3), 128, 0, stream>>>(params);

    const int block = 256;
    const int nh = (N + 1) / 2;
    const int grid = (nh + block - 1) / block;
    spline_evalA<<<grid, block, 0, stream>>>(x, gix, N);
    spline_evalB<<<grid, block, 0, stream>>>(out, N);
}